// Round 2
// baseline (395.573 us; speedup 1.0000x reference)
//
#include <hip/hip_runtime.h>
#include <hip/hip_bf16.h>
#include <stdint.h>

#define N_NODES 100000
#define DIM 128
#define NREL 4
#define NEDGE 500000
#define M_FLAT (NREL * N_NODES)        // 400000 flat (r,node) slots
#define TOT_E (NREL * NEDGE)           // 2M edges
#define NBK ((M_FLAT + 2047) / 2048)   // 196 buckets of 2048 flat slots
#define CHUNK 4096                     // edges per bscatter block

typedef __attribute__((ext_vector_type(8))) short short8;
typedef __attribute__((ext_vector_type(4))) float f32x4;

__device__ __forceinline__ unsigned short f2bf(float f) {
  unsigned int u = __float_as_uint(f);
  u += 0x7fffu + ((u >> 16) & 1u);   // RNE
  return (unsigned short)(u >> 16);
}
__device__ __forceinline__ float bflo(unsigned int v) { return __uint_as_float((v & 0xffffu) << 16); }
__device__ __forceinline__ float bfhi(unsigned int v) { return __uint_as_float((v >> 16) << 16); }

// Combined B in MFMA fragment order. b=0: (sum_r Wself_r)/4 ; b=1+r: Wneigh_r/4.
__global__ void prep_kernel(const float* __restrict__ Ws, const float* __restrict__ Wn,
                            const float* __restrict__ bv, unsigned short* __restrict__ Wt,
                            float* __restrict__ biasc) {
  int tid = blockIdx.x * 256 + threadIdx.x;
  if (tid < 5 * DIM * DIM) {
    int b = tid / (DIM * DIM);
    int idx = tid - b * DIM * DIM;   // k*DIM + n
    int k = idx >> 7, n = idx & 127;
    float v;
    if (b == 0)
      v = 0.25f * (Ws[idx] + Ws[DIM * DIM + idx] + Ws[2 * DIM * DIM + idx] + Ws[3 * DIM * DIM + idx]);
    else
      v = 0.25f * Wn[(b - 1) * DIM * DIM + idx];
    int ks = k >> 5, kq = (k >> 3) & 3, j = k & 7;
    int ct = n >> 4, lr = n & 15;
    int lane = kq * 16 + lr;
    Wt[((((b * 4 + ks) * 8) + ct) * 64 + lane) * 8 + j] = f2bf(v);
  }
  if (tid < DIM)
    biasc[tid] = 0.25f * (bv[tid] + bv[DIM + tid] + bv[2 * DIM + tid] + bv[3 * DIM + tid]);
}

__global__ void xb_kernel(const float* __restrict__ x, unsigned short* __restrict__ xb) {
  int i = blockIdx.x * 256 + threadIdx.x;
  if (i < N_NODES * DIM / 4) {
    float4 v = ((const float4*)x)[i];
    ushort4 s;
    s.x = f2bf(v.x); s.y = f2bf(v.y); s.z = f2bf(v.z); s.w = f2bf(v.w);
    ((ushort4*)xb)[i] = s;
  }
}

// Bucket histogram: LDS-reduced, 196 global atomics per block.
__global__ __launch_bounds__(256) void bhist_kernel(const int* __restrict__ dst,
                                                    int* __restrict__ bcnt) {
  __shared__ int h[NBK];
  int tid = threadIdx.x;
  for (int i = tid; i < NBK; i += 256) h[i] = 0;
  __syncthreads();
  int base = blockIdx.x * 2048;
#pragma unroll
  for (int k = 0; k < 8; ++k) {
    int idx = base + k * 256 + tid;
    if (idx < TOT_E) {
      int r = idx / NEDGE;
      int fl = r * N_NODES + dst[idx];
      atomicAdd(&h[fl >> 11], 1);
    }
  }
  __syncthreads();
  for (int i = tid; i < NBK; i += 256)
    if (h[i]) atomicAdd(&bcnt[i], h[i]);
}

// Scan 196 bucket counts -> boffs[0..NBK], init bcur, set offs[M_FLAT].
__global__ void bscan_kernel(const int* __restrict__ bcnt, int* __restrict__ boffs,
                             int* __restrict__ bcur, int* __restrict__ offs) {
  __shared__ int sh[256];
  int t = threadIdx.x;
  int v = (t < NBK) ? bcnt[t] : 0;
  sh[t] = v;
  __syncthreads();
  for (int o = 1; o < 256; o <<= 1) {
    int u = (t >= o) ? sh[t - o] : 0;
    __syncthreads();
    sh[t] += u;
    __syncthreads();
  }
  int excl = sh[t] - v;
  if (t < NBK) { boffs[t] = excl; bcur[t] = excl; }
  if (t == 255) { boffs[NBK] = sh[t]; offs[M_FLAT] = sh[t]; }
}

// Local sort of a 4096-edge chunk by bucket; coalesced run-writes of packed pairs.
__global__ __launch_bounds__(256) void bscatter_kernel(
    const int* __restrict__ src, const int* __restrict__ dst,
    int* __restrict__ bcur, unsigned int* __restrict__ gpairs) {
  __shared__ unsigned int buf[CHUNK];
  __shared__ unsigned short barr[CHUNK];
  __shared__ int hist[NBK];
  __shared__ int sbase[NBK];
  __shared__ int lcur[NBK];
  __shared__ int gbase[NBK];
  __shared__ int part[256];
  int tid = threadIdx.x;
  int base = blockIdx.x * CHUNK;
  int m = TOT_E - base; if (m > CHUNK) m = CHUNK;
  for (int i = tid; i < NBK; i += 256) { hist[i] = 0; lcur[i] = 0; }
  __syncthreads();
  unsigned int pk[CHUNK / 256];
  int bk[CHUNK / 256];
#pragma unroll
  for (int k = 0; k < CHUNK / 256; ++k) {
    int i = k * 256 + tid;
    int idx = base + i;
    int b = -1; unsigned int p = 0;
    if (i < m) {
      int r = idx / NEDGE;
      int fl = r * N_NODES + dst[idx];
      b = fl >> 11;
      p = ((unsigned int)(fl & 2047) << 17) | (unsigned int)src[idx];
      atomicAdd(&hist[b], 1);
    }
    pk[k] = p; bk[k] = b;
  }
  __syncthreads();
  {
    int v = (tid < NBK) ? hist[tid] : 0;
    part[tid] = v;
    __syncthreads();
    for (int o = 1; o < 256; o <<= 1) {
      int u = (tid >= o) ? part[tid - o] : 0;
      __syncthreads();
      part[tid] += u;
      __syncthreads();
    }
    if (tid < NBK) sbase[tid] = part[tid] - v;
  }
  __syncthreads();
#pragma unroll
  for (int k = 0; k < CHUNK / 256; ++k) {
    if (bk[k] >= 0) {
      int pos = sbase[bk[k]] + atomicAdd(&lcur[bk[k]], 1);
      buf[pos] = pk[k];
      barr[pos] = (unsigned short)bk[k];
    }
  }
  __syncthreads();
  if (tid < NBK && hist[tid] > 0)
    gbase[tid] = atomicAdd(&bcur[tid], hist[tid]) - sbase[tid];
  __syncthreads();
  for (int j = tid; j < m; j += 256)
    gpairs[gbase[barr[j]] + j] = buf[j];
}

// One block per bucket: LDS count + scan -> exact CSR (offs, ssrc).
__global__ __launch_bounds__(256) void bfill_kernel(
    const unsigned int* __restrict__ gpairs, const int* __restrict__ boffs,
    int* __restrict__ offs, int* __restrict__ ssrc) {
  __shared__ int lcnt[2048];
  __shared__ int lofs[2048];
  __shared__ int lcur[2048];
  __shared__ int part[256];
  int b = blockIdx.x;
  int tid = threadIdx.x;
  int base = boffs[b];
  int cntb = boffs[b + 1] - base;
  int flBase = b << 11;
  int flCount = M_FLAT - flBase; if (flCount > 2048) flCount = 2048;
  for (int i = tid; i < 2048; i += 256) { lcnt[i] = 0; lcur[i] = 0; }
  __syncthreads();
  for (int j = tid; j < cntb; j += 256)
    atomicAdd(&lcnt[gpairs[base + j] >> 17], 1);
  __syncthreads();
  int vals[8]; int s0 = 0;
#pragma unroll
  for (int k = 0; k < 8; ++k) { vals[k] = lcnt[tid * 8 + k]; s0 += vals[k]; }
  part[tid] = s0;
  __syncthreads();
  for (int o = 1; o < 256; o <<= 1) {
    int u = (tid >= o) ? part[tid - o] : 0;
    __syncthreads();
    part[tid] += u;
    __syncthreads();
  }
  int excl = part[tid] - s0;
#pragma unroll
  for (int k = 0; k < 8; ++k) { lofs[tid * 8 + k] = excl; excl += vals[k]; }
  __syncthreads();
  for (int i = tid; i < flCount; i += 256)
    offs[flBase + i] = base + lofs[i];
  for (int j = tid; j < cntb; j += 256) {
    unsigned int p = gpairs[base + j];
    int li = p >> 17;
    int pos = atomicAdd(&lcur[li], 1);
    ssrc[base + lofs[li] + pos] = (int)(p & 0x1FFFFu);
  }
}

// Fused aggregate + GEMM. Each wave owns an independent 32-row band:
//  - stages its 32 xb rows into its own XOR-swizzled LDS band (slab 0, self term)
//  - per relation: gathers + means its 32 nodes' neighbor rows straight into the
//    same LDS band, then MFMAs with Wneigh_r/4.
// No __syncthreads anywhere: a wave only ever reads the LDS rows it wrote
// (MFMA A-fragments come from band rows lr / 16+lr), so waves pipeline gather
// and MFMA phases independently. Segment bounds are readfirstlane-scalarized so
// CSR loads / loop control become SALU + scalar loads.
__global__ __launch_bounds__(256, 3) void fused_kernel(
    const unsigned short* __restrict__ xb, const unsigned short* __restrict__ Wt,
    const float* __restrict__ biasc, const int* __restrict__ ssrc,
    const int* __restrict__ offs, float* __restrict__ out) {
  __shared__ unsigned int As[128 * 64];   // 32 KB; 16B units XOR-swizzled by (row&7)
  const unsigned int* xb32 = (const unsigned int*)xb;
  const int tid = threadIdx.x;
  const int lane = tid & 63;
  const int wv = __builtin_amdgcn_readfirstlane(tid >> 6);
  const int bandBase = (blockIdx.x * 4 + wv) * 32;   // N_NODES % 32 == 0: bands all-valid or all-invalid
  if (bandBase >= N_NODES) return;
  const int quad = lane >> 4, lr = lane & 15;
  const short8* Bp = (const short8*)Wt;
  unsigned int* bandA = As + (wv * 32) * 64;

  float bias8[8];
#pragma unroll
  for (int ct = 0; ct < 8; ++ct) bias8[ct] = biasc[ct * 16 + lr];

  f32x4 acc[2][8];
  f32x4 zero = {0.f, 0.f, 0.f, 0.f};
#pragma unroll
  for (int rt = 0; rt < 2; ++rt)
#pragma unroll
    for (int ct = 0; ct < 8; ++ct) acc[rt][ct] = zero;

  // slab 0: stage this wave's 32 xb rows (4 rows x 16 units of 16B per iter).
  // 16 consecutive lanes read one contiguous 256B row -> coalesced.
#pragma unroll
  for (int i = 0; i < 8; ++i) {
    int rloc = i * 4 + (lane >> 4);
    int u = lane & 15;
    short8 v = *(const short8*)(xb + (size_t)(bandBase + rloc) * DIM + u * 8);
    *(short8*)(bandA + rloc * 64 + ((u ^ (rloc & 7)) << 2)) = v;
  }

#define MMA_SLAB(bi)                                                                        \
  {                                                                                         \
    _Pragma("unroll")                                                                       \
    for (int ks = 0; ks < 4; ++ks) {                                                        \
      int u0 = ((ks * 4 + quad) ^ (lr & 7)) << 2;                                           \
      short8 a0 = *(const short8*)(bandA + lr * 64 + u0);                                   \
      short8 a1 = *(const short8*)(bandA + (16 + lr) * 64 + u0);                            \
      _Pragma("unroll")                                                                     \
      for (int ct = 0; ct < 8; ++ct) {                                                      \
        short8 bf = Bp[(((bi) * 4 + ks) * 8 + ct) * 64 + lane];                             \
        acc[0][ct] = __builtin_amdgcn_mfma_f32_16x16x32_bf16(a0, bf, acc[0][ct], 0, 0, 0);  \
        acc[1][ct] = __builtin_amdgcn_mfma_f32_16x16x32_bf16(a1, bf, acc[1][ct], 0, 0, 0);  \
      }                                                                                     \
    }                                                                                       \
  }

  MMA_SLAB(0);

  for (int r = 0; r < NREL; ++r) {
    int flBase = r * N_NODES + bandBase;
    for (int rr = 0; rr < 32; rr += 2) {
      // two adjacent CSR segments (contiguous): A=[sA,eA), B=[eA,eB)
      int sA = __builtin_amdgcn_readfirstlane(offs[flBase + rr]);
      int eA = __builtin_amdgcn_readfirstlane(offs[flBase + rr + 1]);
      int eB = __builtin_amdgcn_readfirstlane(offs[flBase + rr + 2]);
      int cA = eA - sA, cB = eB - eA;
      int ia = sA, ib = eA;
      float aL0 = 0.f, aH0 = 0.f, aL1 = 0.f, aH1 = 0.f;
      while (ia < eA || ib < eB) {   // uniform control: scalar branches only
        int mA = eA - ia, mB = eB - ib;
        unsigned int vA[8], vB[8];
        if (mA > 0) {
#pragma unroll
          for (int k = 0; k < 8; ++k) {
            const unsigned int* rp = xb32 + ((size_t)ssrc[ia + ((k < mA) ? k : (mA - 1))] << 6);
            vA[k] = rp[lane];
          }
        }
        if (mB > 0) {
#pragma unroll
          for (int k = 0; k < 8; ++k) {
            const unsigned int* rp = xb32 + ((size_t)ssrc[ib + ((k < mB) ? k : (mB - 1))] << 6);
            vB[k] = rp[lane];
          }
        }
        if (mA > 0) {
#pragma unroll
          for (int k = 0; k < 8; ++k) {
            unsigned int u = (k < mA) ? vA[k] : 0u;
            aL0 += bflo(u); aH0 += bfhi(u);
          }
          ia += 8;
        }
        if (mB > 0) {
#pragma unroll
          for (int k = 0; k < 8; ++k) {
            unsigned int u = (k < mB) ? vB[k] : 0u;
            aL1 += bflo(u); aH1 += bfhi(u);
          }
          ib += 8;
        }
      }
      float ivA = __builtin_amdgcn_rcpf((float)(cA > 0 ? cA : 1));
      float ivB = __builtin_amdgcn_rcpf((float)(cB > 0 ? cB : 1));
      float l0 = aL0 * ivA, h0 = aH0 * ivA;
      float l1 = aL1 * ivB, h1 = aH1 * ivB;
      unsigned int p0, p1;
      asm("v_cvt_pk_bf16_f32 %0, %1, %2" : "=v"(p0) : "v"(l0), "v"(h0));
      asm("v_cvt_pk_bf16_f32 %0, %1, %2" : "=v"(p1) : "v"(l1), "v"(h1));
      bandA[rr * 64 + (((lane >> 2) ^ (rr & 7)) << 2) + (lane & 3)] = p0;
      bandA[(rr + 1) * 64 + (((lane >> 2) ^ ((rr + 1) & 7)) << 2) + (lane & 3)] = p1;
    }
    MMA_SLAB(r + 1);
  }

#pragma unroll
  for (int rt = 0; rt < 2; ++rt)
#pragma unroll
    for (int i = 0; i < 4; ++i) {
      int g = bandBase + rt * 16 + quad * 4 + i;
#pragma unroll
      for (int ct = 0; ct < 8; ++ct)
        out[(size_t)g * DIM + ct * 16 + lr] = acc[rt][ct][i] + bias8[ct];
    }
}

extern "C" void kernel_launch(void* const* d_in, const int* in_sizes, int n_in,
                              void* d_out, int out_size, void* d_ws, size_t ws_size,
                              hipStream_t stream) {
  const float* x = (const float*)d_in[0];
  const int* src = (const int*)d_in[1];
  const int* dst = (const int*)d_in[2];
  const float* Wself = (const float*)d_in[3];
  const float* Wneigh = (const float*)d_in[4];
  const float* bv = (const float*)d_in[5];
  float* out = (float*)d_out;

  char* ws = (char*)d_ws;
  size_t off = 0;
  int* bcnt = (int*)(ws + off);        off += 1024;
  int* boffs = (int*)(ws + off);       off += 1024;
  int* bcur = (int*)(ws + off);        off += 1024;
  unsigned short* Wt = (unsigned short*)(ws + off);  off += 5 * DIM * DIM * 2;        // 160 KB
  float* biasc = (float*)(ws + off);   off += DIM * 4;
  int* offs = (int*)(ws + off);        off += ((size_t)(M_FLAT + 1) * 4 + 15) & ~15;  // 1.6 MB
  unsigned short* xb = (unsigned short*)(ws + off);  off += (size_t)N_NODES * DIM * 2; // 25.6 MB
  unsigned int* gpairs = (unsigned int*)(ws + off);  off += (size_t)TOT_E * 4;         // 8 MB
  int* ssrc = (int*)(ws + off);        off += (size_t)TOT_E * 4;                       // 8 MB

  hipMemsetAsync(bcnt, 0, 1024, stream);
  xb_kernel<<<(N_NODES * DIM / 4 + 255) / 256, 256, 0, stream>>>(x, xb);
  prep_kernel<<<(5 * DIM * DIM + 255) / 256, 256, 0, stream>>>(Wself, Wneigh, bv, Wt, biasc);
  bhist_kernel<<<(TOT_E + 2047) / 2048, 256, 0, stream>>>(dst, bcnt);
  bscan_kernel<<<1, 256, 0, stream>>>(bcnt, boffs, bcur, offs);
  bscatter_kernel<<<(TOT_E + CHUNK - 1) / CHUNK, 256, 0, stream>>>(src, dst, bcur, gpairs);
  bfill_kernel<<<NBK, 256, 0, stream>>>(gpairs, boffs, offs, ssrc);
  fused_kernel<<<(N_NODES + 127) / 128, 256, 0, stream>>>(xb, Wt, biasc, ssrc, offs, out);
}

// Round 3
// 360.992 us; speedup vs baseline: 1.0958x; 1.0958x over previous
//
#include <hip/hip_runtime.h>
#include <hip/hip_bf16.h>
#include <stdint.h>

#define N_NODES 100000
#define DIM 128
#define NREL 4
#define NEDGE 500000
#define M_FLAT (NREL * N_NODES)        // 400000 flat (r,node) slots
#define TOT_E (NREL * NEDGE)           // 2M edges
#define NBK ((M_FLAT + 2047) / 2048)   // 196 buckets of 2048 flat slots
#define CHUNK 4096                     // edges per bscatter block
#define LDA 136                        // 128 + 8 bf16 pad

typedef __attribute__((ext_vector_type(8))) short short8;
typedef __attribute__((ext_vector_type(4))) float f32x4;
typedef __attribute__((ext_vector_type(2))) float f32x2;

__device__ __forceinline__ unsigned short f2bf(float f) {
  unsigned int u = __float_as_uint(f);
  u += 0x7fffu + ((u >> 16) & 1u);   // RNE
  return (unsigned short)(u >> 16);
}

// Combined B in MFMA fragment order. b=0: (sum_r Wself_r)/4 ; b=1+r: Wneigh_r/4.
__global__ void prep_kernel(const float* __restrict__ Ws, const float* __restrict__ Wn,
                            const float* __restrict__ bv, unsigned short* __restrict__ Wt,
                            float* __restrict__ biasc) {
  int tid = blockIdx.x * 256 + threadIdx.x;
  if (tid < 5 * DIM * DIM) {
    int b = tid / (DIM * DIM);
    int idx = tid - b * DIM * DIM;   // k*DIM + n
    int k = idx >> 7, n = idx & 127;
    float v;
    if (b == 0)
      v = 0.25f * (Ws[idx] + Ws[DIM * DIM + idx] + Ws[2 * DIM * DIM + idx] + Ws[3 * DIM * DIM + idx]);
    else
      v = 0.25f * Wn[(b - 1) * DIM * DIM + idx];
    int ks = k >> 5, kq = (k >> 3) & 3, j = k & 7;
    int ct = n >> 4, lr = n & 15;
    int lane = kq * 16 + lr;
    Wt[((((b * 4 + ks) * 8) + ct) * 64 + lane) * 8 + j] = f2bf(v);
  }
  if (tid < DIM)
    biasc[tid] = 0.25f * (bv[tid] + bv[DIM + tid] + bv[2 * DIM + tid] + bv[3 * DIM + tid]);
}

__global__ void xb_kernel(const float* __restrict__ x, unsigned short* __restrict__ xb) {
  int i = blockIdx.x * 256 + threadIdx.x;
  if (i < N_NODES * DIM / 4) {
    float4 v = ((const float4*)x)[i];
    ushort4 s;
    s.x = f2bf(v.x); s.y = f2bf(v.y); s.z = f2bf(v.z); s.w = f2bf(v.w);
    ((ushort4*)xb)[i] = s;
  }
}

// Bucket histogram: LDS-reduced, 196 global atomics per block.
__global__ __launch_bounds__(256) void bhist_kernel(const int* __restrict__ dst,
                                                    int* __restrict__ bcnt) {
  __shared__ int h[NBK];
  int tid = threadIdx.x;
  for (int i = tid; i < NBK; i += 256) h[i] = 0;
  __syncthreads();
  int base = blockIdx.x * 2048;
#pragma unroll
  for (int k = 0; k < 8; ++k) {
    int idx = base + k * 256 + tid;
    if (idx < TOT_E) {
      int r = idx / NEDGE;
      int fl = r * N_NODES + dst[idx];
      atomicAdd(&h[fl >> 11], 1);
    }
  }
  __syncthreads();
  for (int i = tid; i < NBK; i += 256)
    if (h[i]) atomicAdd(&bcnt[i], h[i]);
}

// Scan 196 bucket counts -> boffs[0..NBK], init bcur, set offs[M_FLAT].
__global__ void bscan_kernel(const int* __restrict__ bcnt, int* __restrict__ boffs,
                             int* __restrict__ bcur, int* __restrict__ offs) {
  __shared__ int sh[256];
  int t = threadIdx.x;
  int v = (t < NBK) ? bcnt[t] : 0;
  sh[t] = v;
  __syncthreads();
  for (int o = 1; o < 256; o <<= 1) {
    int u = (t >= o) ? sh[t - o] : 0;
    __syncthreads();
    sh[t] += u;
    __syncthreads();
  }
  int excl = sh[t] - v;
  if (t < NBK) { boffs[t] = excl; bcur[t] = excl; }
  if (t == 255) { boffs[NBK] = sh[t]; offs[M_FLAT] = sh[t]; }
}

// Local sort of a 4096-edge chunk by bucket; coalesced run-writes of packed pairs.
__global__ __launch_bounds__(256) void bscatter_kernel(
    const int* __restrict__ src, const int* __restrict__ dst,
    int* __restrict__ bcur, unsigned int* __restrict__ gpairs) {
  __shared__ unsigned int buf[CHUNK];
  __shared__ unsigned short barr[CHUNK];
  __shared__ int hist[NBK];
  __shared__ int sbase[NBK];
  __shared__ int lcur[NBK];
  __shared__ int gbase[NBK];
  __shared__ int part[256];
  int tid = threadIdx.x;
  int base = blockIdx.x * CHUNK;
  int m = TOT_E - base; if (m > CHUNK) m = CHUNK;
  for (int i = tid; i < NBK; i += 256) { hist[i] = 0; lcur[i] = 0; }
  __syncthreads();
  unsigned int pk[CHUNK / 256];
  int bk[CHUNK / 256];
#pragma unroll
  for (int k = 0; k < CHUNK / 256; ++k) {
    int i = k * 256 + tid;
    int idx = base + i;
    int b = -1; unsigned int p = 0;
    if (i < m) {
      int r = idx / NEDGE;
      int fl = r * N_NODES + dst[idx];
      b = fl >> 11;
      p = ((unsigned int)(fl & 2047) << 17) | (unsigned int)src[idx];
      atomicAdd(&hist[b], 1);
    }
    pk[k] = p; bk[k] = b;
  }
  __syncthreads();
  {
    int v = (tid < NBK) ? hist[tid] : 0;
    part[tid] = v;
    __syncthreads();
    for (int o = 1; o < 256; o <<= 1) {
      int u = (tid >= o) ? part[tid - o] : 0;
      __syncthreads();
      part[tid] += u;
      __syncthreads();
    }
    if (tid < NBK) sbase[tid] = part[tid] - v;
  }
  __syncthreads();
#pragma unroll
  for (int k = 0; k < CHUNK / 256; ++k) {
    if (bk[k] >= 0) {
      int pos = sbase[bk[k]] + atomicAdd(&lcur[bk[k]], 1);
      buf[pos] = pk[k];
      barr[pos] = (unsigned short)bk[k];
    }
  }
  __syncthreads();
  if (tid < NBK && hist[tid] > 0)
    gbase[tid] = atomicAdd(&bcur[tid], hist[tid]) - sbase[tid];
  __syncthreads();
  for (int j = tid; j < m; j += 256)
    gpairs[gbase[barr[j]] + j] = buf[j];
}

// One block per bucket: LDS count + scan -> exact CSR (offs, ssrc).
__global__ __launch_bounds__(256) void bfill_kernel(
    const unsigned int* __restrict__ gpairs, const int* __restrict__ boffs,
    int* __restrict__ offs, int* __restrict__ ssrc) {
  __shared__ int lcnt[2048];
  __shared__ int lofs[2048];
  __shared__ int lcur[2048];
  __shared__ int part[256];
  int b = blockIdx.x;
  int tid = threadIdx.x;
  int base = boffs[b];
  int cntb = boffs[b + 1] - base;
  int flBase = b << 11;
  int flCount = M_FLAT - flBase; if (flCount > 2048) flCount = 2048;
  for (int i = tid; i < 2048; i += 256) { lcnt[i] = 0; lcur[i] = 0; }
  __syncthreads();
  for (int j = tid; j < cntb; j += 256)
    atomicAdd(&lcnt[gpairs[base + j] >> 17], 1);
  __syncthreads();
  int vals[8]; int s0 = 0;
#pragma unroll
  for (int k = 0; k < 8; ++k) { vals[k] = lcnt[tid * 8 + k]; s0 += vals[k]; }
  part[tid] = s0;
  __syncthreads();
  for (int o = 1; o < 256; o <<= 1) {
    int u = (tid >= o) ? part[tid - o] : 0;
    __syncthreads();
    part[tid] += u;
    __syncthreads();
  }
  int excl = part[tid] - s0;
#pragma unroll
  for (int k = 0; k < 8; ++k) { lofs[tid * 8 + k] = excl; excl += vals[k]; }
  __syncthreads();
  for (int i = tid; i < flCount; i += 256)
    offs[flBase + i] = base + lofs[i];
  for (int j = tid; j < cntb; j += 256) {
    unsigned int p = gpairs[base + j];
    int li = p >> 17;
    int pos = atomicAdd(&lcur[li], 1);
    ssrc[base + lofs[li] + pos] = (int)(p & 0x1FFFFu);
  }
}

// One wave per node: per relation gather xb[src] rows, mean in f32, write agg bf16.
// VALU-lean inner loop: scalarized segment bounds (uniform loop control + scalar
// ssrc loads), 32-bit SGPR-base gather addressing (1 VALU/slot), single shl/and
// unpack + packed f32 add (v_pk_add_f32), cvt_pk epilogue.
__global__ __launch_bounds__(256) void aggregate_kernel(
    const unsigned int* __restrict__ xb32, const int* __restrict__ ssrc,
    const int* __restrict__ offs, unsigned int* __restrict__ agg32,
    int rLo, int rHi, int slabBase) {
  int lane = threadIdx.x & 63;
  int n = blockIdx.x * 4 + (threadIdx.x >> 6);
  if (n >= N_NODES) return;
  for (int r = rLo; r < rHi; ++r) {
    int fl = r * N_NODES + n;
    int start = __builtin_amdgcn_readfirstlane(offs[fl]);
    int end = __builtin_amdgcn_readfirstlane(offs[fl + 1]);
    int c = end - start;
    f32x2 acc = {0.f, 0.f};
    for (int e = start; e < end; e += 8) {
      int m = end - e;   // wave-uniform
      unsigned int v[8];
#pragma unroll
      for (int k = 0; k < 8; ++k) {
        int idx = ssrc[e + ((k < m) ? k : 0)];                 // uniform index
        v[k] = xb32[((unsigned)idx << 6) | (unsigned)lane];    // sgpr-base + voffset
      }
#pragma unroll
      for (int k = 0; k < 8; ++k) {
        unsigned int u = (k < m) ? v[k] : 0u;
        f32x2 d;
        d.x = __uint_as_float(u << 16);          // low bf16
        d.y = __uint_as_float(u & 0xffff0000u);  // high bf16
        acc += d;                                 // v_pk_add_f32
      }
    }
    float inv = __builtin_amdgcn_rcpf((float)(c > 0 ? c : 1));
    float lo = acc.x * inv, hi = acc.y * inv;
    unsigned int packed;
    asm("v_cvt_pk_bf16_f32 %0, %1, %2" : "=v"(packed) : "v"(lo), "v"(hi));
    agg32[((size_t)(r - slabBase) * N_NODES + n) * 64 + lane] = packed;
  }
}

// K-slab GEMM over bf16 A sources (bi=0: xb; bi>=1: agg slab), acc held in AGPRs.
__global__ __launch_bounds__(256) void gemm_kernel(
    const unsigned short* __restrict__ xb, const unsigned short* __restrict__ Wt,
    const float* __restrict__ biasc, float* __restrict__ out,
    const unsigned short* __restrict__ agg, int slabBase, int bLo, int bHi, int accum) {
  __shared__ unsigned short As[128][LDA];
  int tid = threadIdx.x;
  int rowBase = blockIdx.x * 128;
  int lane = tid & 63;
  int wv = tid >> 6;
  int quad = lane >> 4;
  int lr = lane & 15;
  const short8* Bp = (const short8*)Wt;

  float bias8[8];
#pragma unroll
  for (int ct = 0; ct < 8; ++ct) bias8[ct] = biasc[ct * 16 + lr];

  f32x4 zero = {0.f, 0.f, 0.f, 0.f};
  f32x4 acc[2][8];
#pragma unroll
  for (int rt = 0; rt < 2; ++rt)
#pragma unroll
    for (int ct = 0; ct < 8; ++ct) acc[rt][ct] = zero;

  for (int bi = bLo; bi <= bHi; ++bi) {
    if (bi > bLo) __syncthreads();
    const unsigned short* as =
        (bi == 0) ? xb : agg + (size_t)(bi - 1 - slabBase) * N_NODES * DIM;
#pragma unroll
    for (int p = 0; p < 8; ++p) {
      int unit = p * 256 + tid;          // 2048 units of 8 bf16
      int row = unit >> 4;
      int c8 = unit & 15;
      int g = rowBase + row;
      short8 val = {0, 0, 0, 0, 0, 0, 0, 0};
      if (g < N_NODES) val = *(const short8*)(as + (size_t)g * DIM + c8 * 8);
      *(short8*)&As[row][c8 * 8] = val;
    }
    __syncthreads();

#pragma unroll
    for (int ks = 0; ks < 4; ++ks) {
      int k0 = ks * 32 + quad * 8;
      short8 a0 = *(const short8*)&As[wv * 32 + lr][k0];
      short8 a1 = *(const short8*)&As[wv * 32 + 16 + lr][k0];
#pragma unroll
      for (int ct = 0; ct < 8; ++ct) {
        short8 bf = Bp[((bi * 4 + ks) * 8 + ct) * 64 + lane];
        acc[0][ct] = __builtin_amdgcn_mfma_f32_16x16x32_bf16(a0, bf, acc[0][ct], 0, 0, 0);
        acc[1][ct] = __builtin_amdgcn_mfma_f32_16x16x32_bf16(a1, bf, acc[1][ct], 0, 0, 0);
      }
    }
  }

#pragma unroll
  for (int rt = 0; rt < 2; ++rt)
#pragma unroll
    for (int i = 0; i < 4; ++i) {
      int g = rowBase + wv * 32 + rt * 16 + quad * 4 + i;
      if (g < N_NODES) {
        if (accum == 0) {
#pragma unroll
          for (int ct = 0; ct < 8; ++ct)
            out[(size_t)g * DIM + ct * 16 + lr] = acc[rt][ct][i] + bias8[ct];
        } else {
#pragma unroll
          for (int ct = 0; ct < 8; ++ct)
            out[(size_t)g * DIM + ct * 16 + lr] += acc[rt][ct][i];
        }
      }
    }
}

extern "C" void kernel_launch(void* const* d_in, const int* in_sizes, int n_in,
                              void* d_out, int out_size, void* d_ws, size_t ws_size,
                              hipStream_t stream) {
  const float* x = (const float*)d_in[0];
  const int* src = (const int*)d_in[1];
  const int* dst = (const int*)d_in[2];
  const float* Wself = (const float*)d_in[3];
  const float* Wneigh = (const float*)d_in[4];
  const float* bv = (const float*)d_in[5];
  float* out = (float*)d_out;

  char* ws = (char*)d_ws;
  size_t off = 0;
  int* bcnt = (int*)(ws + off);        off += 1024;
  int* boffs = (int*)(ws + off);       off += 1024;
  int* bcur = (int*)(ws + off);        off += 1024;
  unsigned short* Wt = (unsigned short*)(ws + off);  off += 5 * DIM * DIM * 2;        // 160 KB
  float* biasc = (float*)(ws + off);   off += DIM * 4;
  int* offs = (int*)(ws + off);        off += ((size_t)(M_FLAT + 1) * 4 + 15) & ~15;  // 1.6 MB
  unsigned short* xb = (unsigned short*)(ws + off);  off += (size_t)N_NODES * DIM * 2; // 25.6 MB
  unsigned int* gpairs = (unsigned int*)(ws + off);  off += (size_t)TOT_E * 4;         // 8 MB
  int* ssrc = (int*)(ws + off);        off += (size_t)TOT_E * 4;                       // 8 MB
  unsigned short* agg = (unsigned short*)(ws + off);
  size_t slabBytes = (size_t)N_NODES * DIM * 2;                                        // 25.6 MB

  int sc = 0;
  while (sc < NREL && ws_size >= off + (size_t)(sc + 1) * slabBytes) sc++;
  if (sc < 1) sc = 1;

  hipMemsetAsync(bcnt, 0, 1024, stream);
  xb_kernel<<<(N_NODES * DIM / 4 + 255) / 256, 256, 0, stream>>>(x, xb);
  prep_kernel<<<(5 * DIM * DIM + 255) / 256, 256, 0, stream>>>(Wself, Wneigh, bv, Wt, biasc);
  bhist_kernel<<<(TOT_E + 2047) / 2048, 256, 0, stream>>>(dst, bcnt);
  bscan_kernel<<<1, 256, 0, stream>>>(bcnt, boffs, bcur, offs);
  bscatter_kernel<<<(TOT_E + CHUNK - 1) / CHUNK, 256, 0, stream>>>(src, dst, bcur, gpairs);
  bfill_kernel<<<NBK, 256, 0, stream>>>(gpairs, boffs, offs, ssrc);

  int gAgg = (N_NODES + 3) / 4;       // wave per node
  int gGemm = (N_NODES + 127) / 128;  // 782
  for (int r0 = 0; r0 < NREL; r0 += sc) {
    int cr = (NREL - r0 < sc) ? (NREL - r0) : sc;
    aggregate_kernel<<<gAgg, 256, 0, stream>>>((const unsigned int*)xb, ssrc, offs,
                                               (unsigned int*)agg, r0, r0 + cr, r0);
    int bLo = (r0 == 0) ? 0 : (1 + r0);
    gemm_kernel<<<gGemm, 256, 0, stream>>>(xb, Wt, biasc, out, agg, r0, bLo, r0 + cr,
                                           (r0 == 0) ? 0 : 1);
  }
}

// Round 4
// 360.374 us; speedup vs baseline: 1.0977x; 1.0017x over previous
//
#include <hip/hip_runtime.h>
#include <hip/hip_bf16.h>
#include <stdint.h>

#define N_NODES 100000
#define DIM 128
#define NREL 4
#define NEDGE 500000
#define M_FLAT (NREL * N_NODES)        // 400000 flat (r,node) slots
#define TOT_E (NREL * NEDGE)           // 2M edges
#define BSLOT 1024                     // flat slots per bucket
#define NBK ((M_FLAT + BSLOT - 1) / BSLOT)   // 391 buckets
#define CAP 8192                       // padded edge capacity per bucket (mean 5120, 43 sigma slack)
#define CHUNK 4096                     // edges per bscatter block

typedef __attribute__((ext_vector_type(8))) short short8;
typedef __attribute__((ext_vector_type(4))) float f32x4;
typedef __attribute__((ext_vector_type(2))) float f32x2;

__device__ __forceinline__ unsigned short f2bf(float f) {
  unsigned int u = __float_as_uint(f);
  u += 0x7fffu + ((u >> 16) & 1u);   // RNE
  return (unsigned short)(u >> 16);
}

// Combined B in MFMA fragment order. b=0: (sum_r Wself_r)/4 ; b=1+r: Wneigh_r/4.
__global__ void prep_kernel(const float* __restrict__ Ws, const float* __restrict__ Wn,
                            const float* __restrict__ bv, unsigned short* __restrict__ Wt,
                            float* __restrict__ biasc) {
  int tid = blockIdx.x * 256 + threadIdx.x;
  if (tid < 5 * DIM * DIM) {
    int b = tid / (DIM * DIM);
    int idx = tid - b * DIM * DIM;   // k*DIM + n
    int k = idx >> 7, n = idx & 127;
    float v;
    if (b == 0)
      v = 0.25f * (Ws[idx] + Ws[DIM * DIM + idx] + Ws[2 * DIM * DIM + idx] + Ws[3 * DIM * DIM + idx]);
    else
      v = 0.25f * Wn[(b - 1) * DIM * DIM + idx];
    int ks = k >> 5, kq = (k >> 3) & 3, j = k & 7;
    int ct = n >> 4, lr = n & 15;
    int lane = kq * 16 + lr;
    Wt[((((b * 4 + ks) * 8) + ct) * 64 + lane) * 8 + j] = f2bf(v);
  }
  if (tid < DIM)
    biasc[tid] = 0.25f * (bv[tid] + bv[DIM + tid] + bv[2 * DIM + tid] + bv[3 * DIM + tid]);
}

__global__ void xb_kernel(const float* __restrict__ x, unsigned short* __restrict__ xb) {
  int i = blockIdx.x * 256 + threadIdx.x;
  if (i < N_NODES * DIM / 4) {
    float4 v = ((const float4*)x)[i];
    ushort4 s;
    s.x = f2bf(v.x); s.y = f2bf(v.y); s.z = f2bf(v.z); s.w = f2bf(v.w);
    ((ushort4*)xb)[i] = s;
  }
}

// Local sort of a 4096-edge chunk by bucket; coalesced run-writes of packed pairs
// into padded per-bucket regions (placement via one global atomic per bucket).
__global__ __launch_bounds__(256) void bscatter_kernel(
    const int* __restrict__ src, const int* __restrict__ dst,
    int* __restrict__ bcnt, unsigned int* __restrict__ gpairs) {
  __shared__ unsigned int buf[CHUNK];
  __shared__ unsigned short barr[CHUNK];
  __shared__ int hist[NBK];
  __shared__ int sbase[NBK];
  __shared__ int lcur[NBK];
  __shared__ int gbase[NBK];
  __shared__ int part[256];
  int tid = threadIdx.x;
  int base = blockIdx.x * CHUNK;
  int m = TOT_E - base; if (m > CHUNK) m = CHUNK;
  for (int i = tid; i < NBK; i += 256) { hist[i] = 0; lcur[i] = 0; }
  __syncthreads();
  unsigned int pk[CHUNK / 256];
  int bk[CHUNK / 256];
#pragma unroll
  for (int k = 0; k < CHUNK / 256; ++k) {
    int i = k * 256 + tid;
    int idx = base + i;
    int b = -1; unsigned int p = 0;
    if (i < m) {
      int r = idx / NEDGE;
      int fl = r * N_NODES + dst[idx];
      b = fl >> 10;
      p = ((unsigned int)(fl & (BSLOT - 1)) << 17) | (unsigned int)src[idx];
      atomicAdd(&hist[b], 1);
    }
    pk[k] = p; bk[k] = b;
  }
  __syncthreads();
  // two-pass exclusive scan over hist[0..NBK) (NBK = 391 > 256)
  {
    int vA = hist[tid];
    part[tid] = vA;
    __syncthreads();
    for (int o = 1; o < 256; o <<= 1) {
      int u = (tid >= o) ? part[tid - o] : 0;
      __syncthreads();
      part[tid] += u;
      __syncthreads();
    }
    sbase[tid] = part[tid] - vA;
    int totalA = part[255];
    __syncthreads();
    int vB = (256 + tid < NBK) ? hist[256 + tid] : 0;
    part[tid] = vB;
    __syncthreads();
    for (int o = 1; o < 256; o <<= 1) {
      int u = (tid >= o) ? part[tid - o] : 0;
      __syncthreads();
      part[tid] += u;
      __syncthreads();
    }
    if (256 + tid < NBK) sbase[256 + tid] = totalA + part[tid] - vB;
  }
  __syncthreads();
#pragma unroll
  for (int k = 0; k < CHUNK / 256; ++k) {
    if (bk[k] >= 0) {
      int pos = sbase[bk[k]] + atomicAdd(&lcur[bk[k]], 1);
      buf[pos] = pk[k];
      barr[pos] = (unsigned short)bk[k];
    }
  }
  __syncthreads();
  for (int i = tid; i < NBK; i += 256)
    if (hist[i] > 0) gbase[i] = i * CAP + atomicAdd(&bcnt[i], hist[i]) - sbase[i];
  __syncthreads();
  for (int j = tid; j < m; j += 256)
    gpairs[gbase[barr[j]] + j] = buf[j];
}

// One block per bucket: LDS count + scan -> exact CSR within padded bucket region.
// offs is bucket-strided: 1025 entries per bucket (slot starts + bucket end),
// consumer index = fl + (fl >> 10).
__global__ __launch_bounds__(256) void bfill_kernel(
    const unsigned int* __restrict__ gpairs, const int* __restrict__ bcnt,
    int* __restrict__ offs, int* __restrict__ ssrc) {
  __shared__ int lcnt[BSLOT];
  __shared__ int lofs[BSLOT];
  __shared__ int lcur[BSLOT];
  __shared__ int part[256];
  int b = blockIdx.x;
  int tid = threadIdx.x;
  int base = b * CAP;
  int cntb = bcnt[b];
  int flBase = b << 10;
  int flCount = M_FLAT - flBase; if (flCount > BSLOT) flCount = BSLOT;
  for (int i = tid; i < BSLOT; i += 256) { lcnt[i] = 0; lcur[i] = 0; }
  __syncthreads();
  for (int j = tid; j < cntb; j += 256)
    atomicAdd(&lcnt[gpairs[base + j] >> 17], 1);
  __syncthreads();
  int vals[4]; int s0 = 0;
#pragma unroll
  for (int k = 0; k < 4; ++k) { vals[k] = lcnt[tid * 4 + k]; s0 += vals[k]; }
  part[tid] = s0;
  __syncthreads();
  for (int o = 1; o < 256; o <<= 1) {
    int u = (tid >= o) ? part[tid - o] : 0;
    __syncthreads();
    part[tid] += u;
    __syncthreads();
  }
  int excl = part[tid] - s0;
#pragma unroll
  for (int k = 0; k < 4; ++k) { lofs[tid * 4 + k] = excl; excl += vals[k]; }
  __syncthreads();
  for (int i = tid; i <= flCount; i += 256)
    offs[b * (BSLOT + 1) + i] = base + ((i < BSLOT) ? lofs[i] : cntb);
  for (int j = tid; j < cntb; j += 256) {
    unsigned int p = gpairs[base + j];
    int li = p >> 17;
    int pos = atomicAdd(&lcur[li], 1);
    ssrc[base + lofs[li] + pos] = (int)(p & 0x1FFFFu);
  }
}

// One wave per node: per relation gather xb[src] rows, mean in f32, write agg bf16.
// Scalarized segment bounds, 32-bit SGPR-base gather addressing, packed f32 add.
__global__ __launch_bounds__(256) void aggregate_kernel(
    const unsigned int* __restrict__ xb32, const int* __restrict__ ssrc,
    const int* __restrict__ offs, unsigned int* __restrict__ agg32,
    int rLo, int rHi, int slabBase) {
  int lane = threadIdx.x & 63;
  int n = blockIdx.x * 4 + (threadIdx.x >> 6);
  if (n >= N_NODES) return;
  for (int r = rLo; r < rHi; ++r) {
    int fl = r * N_NODES + n;
    int oidx = fl + (fl >> 10);   // bucket-strided offs index
    int start = __builtin_amdgcn_readfirstlane(offs[oidx]);
    int end = __builtin_amdgcn_readfirstlane(offs[oidx + 1]);
    int c = end - start;
    f32x2 acc = {0.f, 0.f};
    for (int e = start; e < end; e += 8) {
      int m = end - e;   // wave-uniform
      unsigned int v[8];
#pragma unroll
      for (int k = 0; k < 8; ++k) {
        int idx = ssrc[e + ((k < m) ? k : 0)];                 // uniform index
        v[k] = xb32[((unsigned)idx << 6) | (unsigned)lane];    // sgpr-base + voffset
      }
#pragma unroll
      for (int k = 0; k < 8; ++k) {
        unsigned int u = (k < m) ? v[k] : 0u;
        f32x2 d;
        d.x = __uint_as_float(u << 16);          // low bf16
        d.y = __uint_as_float(u & 0xffff0000u);  // high bf16
        acc += d;                                 // v_pk_add_f32
      }
    }
    float inv = __builtin_amdgcn_rcpf((float)(c > 0 ? c : 1));
    float lo = acc.x * inv, hi = acc.y * inv;
    unsigned int packed;
    asm("v_cvt_pk_bf16_f32 %0, %1, %2" : "=v"(packed) : "v"(lo), "v"(hi));
    agg32[((size_t)(r - slabBase) * N_NODES + n) * 64 + lane] = packed;
  }
}

// LDS-free GEMM: each wave owns a 32-row band; every A-row is consumed by exactly
// one wave, so MFMA A-fragments are loaded DIRECTLY from global (per (row,ks) the
// 4 quad-lanes form a contiguous 64B chunk; each row read exactly once). No
// barriers, no LDS staging. Band validity is wave-uniform (N_NODES % 32 == 0).
__global__ __launch_bounds__(256) void gemm_kernel(
    const unsigned short* __restrict__ xb, const unsigned short* __restrict__ Wt,
    const float* __restrict__ biasc, float* __restrict__ out,
    const unsigned short* __restrict__ agg, int slabBase, int bLo, int bHi, int accum) {
  int tid = threadIdx.x;
  int lane = tid & 63;
  int wv = __builtin_amdgcn_readfirstlane(tid >> 6);
  int bandRow = blockIdx.x * 128 + wv * 32;
  if (bandRow >= N_NODES) return;
  int quad = lane >> 4;
  int lr = lane & 15;
  const short8* Bp = (const short8*)Wt;

  float bias8[8];
#pragma unroll
  for (int ct = 0; ct < 8; ++ct) bias8[ct] = biasc[ct * 16 + lr];

  f32x4 zero = {0.f, 0.f, 0.f, 0.f};
  f32x4 acc[2][8];
#pragma unroll
  for (int rt = 0; rt < 2; ++rt)
#pragma unroll
    for (int ct = 0; ct < 8; ++ct) acc[rt][ct] = zero;

  for (int bi = bLo; bi <= bHi; ++bi) {
    const unsigned short* as =
        (bi == 0) ? xb : agg + (size_t)(bi - 1 - slabBase) * N_NODES * DIM;
    const unsigned short* rowp = as + (size_t)(bandRow + lr) * DIM;
#pragma unroll
    for (int ks = 0; ks < 4; ++ks) {
      int k0 = ks * 32 + quad * 8;
      short8 a0 = *(const short8*)(rowp + k0);
      short8 a1 = *(const short8*)(rowp + 16 * DIM + k0);
#pragma unroll
      for (int ct = 0; ct < 8; ++ct) {
        short8 bf = Bp[((bi * 4 + ks) * 8 + ct) * 64 + lane];
        acc[0][ct] = __builtin_amdgcn_mfma_f32_16x16x32_bf16(a0, bf, acc[0][ct], 0, 0, 0);
        acc[1][ct] = __builtin_amdgcn_mfma_f32_16x16x32_bf16(a1, bf, acc[1][ct], 0, 0, 0);
      }
    }
  }

#pragma unroll
  for (int rt = 0; rt < 2; ++rt)
#pragma unroll
    for (int i = 0; i < 4; ++i) {
      int g = bandRow + rt * 16 + quad * 4 + i;
      if (accum == 0) {
#pragma unroll
        for (int ct = 0; ct < 8; ++ct)
          out[(size_t)g * DIM + ct * 16 + lr] = acc[rt][ct][i] + bias8[ct];
      } else {
#pragma unroll
        for (int ct = 0; ct < 8; ++ct)
          out[(size_t)g * DIM + ct * 16 + lr] += acc[rt][ct][i];
      }
    }
}

extern "C" void kernel_launch(void* const* d_in, const int* in_sizes, int n_in,
                              void* d_out, int out_size, void* d_ws, size_t ws_size,
                              hipStream_t stream) {
  const float* x = (const float*)d_in[0];
  const int* src = (const int*)d_in[1];
  const int* dst = (const int*)d_in[2];
  const float* Wself = (const float*)d_in[3];
  const float* Wneigh = (const float*)d_in[4];
  const float* bv = (const float*)d_in[5];
  float* out = (float*)d_out;

  char* ws = (char*)d_ws;
  size_t off = 0;
  int* bcnt = (int*)(ws + off);        off += 2048;                                    // 391 cursors
  unsigned short* Wt = (unsigned short*)(ws + off);  off += 5 * DIM * DIM * 2;         // 160 KB
  float* biasc = (float*)(ws + off);   off += DIM * 4;
  int* offs = (int*)(ws + off);        off += ((size_t)NBK * (BSLOT + 1) * 4 + 15) & ~15;  // 1.6 MB
  unsigned short* xb = (unsigned short*)(ws + off);  off += (size_t)N_NODES * DIM * 2;  // 25.6 MB
  unsigned int* gpairs = (unsigned int*)(ws + off);  off += (size_t)NBK * CAP * 4;      // 12.8 MB
  int* ssrc = (int*)(ws + off);        off += (size_t)NBK * CAP * 4;                    // 12.8 MB
  unsigned short* agg = (unsigned short*)(ws + off);
  size_t slabBytes = (size_t)N_NODES * DIM * 2;                                         // 25.6 MB

  int sc = 0;
  while (sc < NREL && ws_size >= off + (size_t)(sc + 1) * slabBytes) sc++;
  if (sc < 1) sc = 1;

  hipMemsetAsync(bcnt, 0, 2048, stream);
  xb_kernel<<<(N_NODES * DIM / 4 + 255) / 256, 256, 0, stream>>>(x, xb);
  prep_kernel<<<(5 * DIM * DIM + 255) / 256, 256, 0, stream>>>(Wself, Wneigh, bv, Wt, biasc);
  bscatter_kernel<<<(TOT_E + CHUNK - 1) / CHUNK, 256, 0, stream>>>(src, dst, bcnt, gpairs);
  bfill_kernel<<<NBK, 256, 0, stream>>>(gpairs, bcnt, offs, ssrc);

  int gAgg = (N_NODES + 3) / 4;       // wave per node
  int gGemm = (N_NODES + 127) / 128;  // 782
  for (int r0 = 0; r0 < NREL; r0 += sc) {
    int cr = (NREL - r0 < sc) ? (NREL - r0) : sc;
    aggregate_kernel<<<gAgg, 256, 0, stream>>>((const unsigned int*)xb, ssrc, offs,
                                               (unsigned int*)agg, r0, r0 + cr, r0);
    int bLo = (r0 == 0) ? 0 : (1 + r0);
    gemm_kernel<<<gGemm, 256, 0, stream>>>(xb, Wt, biasc, out, agg, r0, bLo, r0 + cr,
                                           (r0 == 0) ? 0 : 1);
  }
}

// Round 5
// 301.577 us; speedup vs baseline: 1.3117x; 1.1950x over previous
//
#include <hip/hip_runtime.h>
#include <hip/hip_bf16.h>
#include <stdint.h>

#define N_NODES 100000
#define DIM 128
#define NREL 4
#define NEDGE 500000
#define M_FLAT (NREL * N_NODES)        // 400000 flat (r,node) slots
#define TOT_E (NREL * NEDGE)           // 2M edges
#define BSLOT 1024                     // flat slots per bucket
#define NBK ((M_FLAT + BSLOT - 1) / BSLOT)   // 391 buckets
#define CAP 8192                       // padded edge capacity per bucket (mean 5120, 43 sigma slack)
#define CHUNK 4096                     // edges per bscatter block

typedef __attribute__((ext_vector_type(8))) short short8;
typedef __attribute__((ext_vector_type(4))) float f32x4;
typedef __attribute__((ext_vector_type(2))) float f32x2;

__device__ __forceinline__ unsigned short f2bf(float f) {
  unsigned int u = __float_as_uint(f);
  u += 0x7fffu + ((u >> 16) & 1u);   // RNE
  return (unsigned short)(u >> 16);
}

// Combined B in MFMA fragment order. b=0: (sum_r Wself_r)/4 ; b=1+r: Wneigh_r/4.
__global__ void prep_kernel(const float* __restrict__ Ws, const float* __restrict__ Wn,
                            const float* __restrict__ bv, unsigned short* __restrict__ Wt,
                            float* __restrict__ biasc) {
  int tid = blockIdx.x * 256 + threadIdx.x;
  if (tid < 5 * DIM * DIM) {
    int b = tid / (DIM * DIM);
    int idx = tid - b * DIM * DIM;   // k*DIM + n
    int k = idx >> 7, n = idx & 127;
    float v;
    if (b == 0)
      v = 0.25f * (Ws[idx] + Ws[DIM * DIM + idx] + Ws[2 * DIM * DIM + idx] + Ws[3 * DIM * DIM + idx]);
    else
      v = 0.25f * Wn[(b - 1) * DIM * DIM + idx];
    int ks = k >> 5, kq = (k >> 3) & 3, j = k & 7;
    int ct = n >> 4, lr = n & 15;
    int lane = kq * 16 + lr;
    Wt[((((b * 4 + ks) * 8) + ct) * 64 + lane) * 8 + j] = f2bf(v);
  }
  if (tid < DIM)
    biasc[tid] = 0.25f * (bv[tid] + bv[DIM + tid] + bv[2 * DIM + tid] + bv[3 * DIM + tid]);
}

__global__ void xb_kernel(const float* __restrict__ x, unsigned short* __restrict__ xb) {
  int i = blockIdx.x * 256 + threadIdx.x;
  if (i < N_NODES * DIM / 4) {
    float4 v = ((const float4*)x)[i];
    ushort4 s;
    s.x = f2bf(v.x); s.y = f2bf(v.y); s.z = f2bf(v.z); s.w = f2bf(v.w);
    ((ushort4*)xb)[i] = s;
  }
}

// Local sort of a 4096-edge chunk by bucket; coalesced run-writes of packed pairs
// into padded per-bucket regions (placement via one global atomic per bucket).
__global__ __launch_bounds__(256) void bscatter_kernel(
    const int* __restrict__ src, const int* __restrict__ dst,
    int* __restrict__ bcnt, unsigned int* __restrict__ gpairs) {
  __shared__ unsigned int buf[CHUNK];
  __shared__ unsigned short barr[CHUNK];
  __shared__ int hist[NBK];
  __shared__ int sbase[NBK];
  __shared__ int lcur[NBK];
  __shared__ int gbase[NBK];
  __shared__ int part[256];
  int tid = threadIdx.x;
  int base = blockIdx.x * CHUNK;
  int m = TOT_E - base; if (m > CHUNK) m = CHUNK;
  for (int i = tid; i < NBK; i += 256) { hist[i] = 0; lcur[i] = 0; }
  __syncthreads();
  unsigned int pk[CHUNK / 256];
  int bk[CHUNK / 256];
#pragma unroll
  for (int k = 0; k < CHUNK / 256; ++k) {
    int i = k * 256 + tid;
    int idx = base + i;
    int b = -1; unsigned int p = 0;
    if (i < m) {
      int r = idx / NEDGE;
      int fl = r * N_NODES + dst[idx];
      b = fl >> 10;
      p = ((unsigned int)(fl & (BSLOT - 1)) << 17) | (unsigned int)src[idx];
      atomicAdd(&hist[b], 1);
    }
    pk[k] = p; bk[k] = b;
  }
  __syncthreads();
  // two-pass exclusive scan over hist[0..NBK) (NBK = 391 > 256)
  {
    int vA = hist[tid];
    part[tid] = vA;
    __syncthreads();
    for (int o = 1; o < 256; o <<= 1) {
      int u = (tid >= o) ? part[tid - o] : 0;
      __syncthreads();
      part[tid] += u;
      __syncthreads();
    }
    sbase[tid] = part[tid] - vA;
    int totalA = part[255];
    __syncthreads();
    int vB = (256 + tid < NBK) ? hist[256 + tid] : 0;
    part[tid] = vB;
    __syncthreads();
    for (int o = 1; o < 256; o <<= 1) {
      int u = (tid >= o) ? part[tid - o] : 0;
      __syncthreads();
      part[tid] += u;
      __syncthreads();
    }
    if (256 + tid < NBK) sbase[256 + tid] = totalA + part[tid] - vB;
  }
  __syncthreads();
#pragma unroll
  for (int k = 0; k < CHUNK / 256; ++k) {
    if (bk[k] >= 0) {
      int pos = sbase[bk[k]] + atomicAdd(&lcur[bk[k]], 1);
      buf[pos] = pk[k];
      barr[pos] = (unsigned short)bk[k];
    }
  }
  __syncthreads();
  for (int i = tid; i < NBK; i += 256)
    if (hist[i] > 0) gbase[i] = i * CAP + atomicAdd(&bcnt[i], hist[i]) - sbase[i];
  __syncthreads();
  for (int j = tid; j < m; j += 256)
    gpairs[gbase[barr[j]] + j] = buf[j];
}

// One block per bucket: LDS count + scan -> exact CSR within padded bucket region.
// offs is bucket-strided: 1025 entries per bucket (slot starts + bucket end),
// consumer index = fl + (fl >> 10).
__global__ __launch_bounds__(256) void bfill_kernel(
    const unsigned int* __restrict__ gpairs, const int* __restrict__ bcnt,
    int* __restrict__ offs, int* __restrict__ ssrc) {
  __shared__ int lcnt[BSLOT];
  __shared__ int lofs[BSLOT];
  __shared__ int lcur[BSLOT];
  __shared__ int part[256];
  int b = blockIdx.x;
  int tid = threadIdx.x;
  int base = b * CAP;
  int cntb = bcnt[b];
  int flBase = b << 10;
  int flCount = M_FLAT - flBase; if (flCount > BSLOT) flCount = BSLOT;
  for (int i = tid; i < BSLOT; i += 256) { lcnt[i] = 0; lcur[i] = 0; }
  __syncthreads();
  for (int j = tid; j < cntb; j += 256)
    atomicAdd(&lcnt[gpairs[base + j] >> 17], 1);
  __syncthreads();
  int vals[4]; int s0 = 0;
#pragma unroll
  for (int k = 0; k < 4; ++k) { vals[k] = lcnt[tid * 4 + k]; s0 += vals[k]; }
  part[tid] = s0;
  __syncthreads();
  for (int o = 1; o < 256; o <<= 1) {
    int u = (tid >= o) ? part[tid - o] : 0;
    __syncthreads();
    part[tid] += u;
    __syncthreads();
  }
  int excl = part[tid] - s0;
#pragma unroll
  for (int k = 0; k < 4; ++k) { lofs[tid * 4 + k] = excl; excl += vals[k]; }
  __syncthreads();
  for (int i = tid; i <= flCount; i += 256)
    offs[b * (BSLOT + 1) + i] = base + ((i < BSLOT) ? lofs[i] : cntb);
  for (int j = tid; j < cntb; j += 256) {
    unsigned int p = gpairs[base + j];
    int li = p >> 17;
    int pos = atomicAdd(&lcur[li], 1);
    ssrc[base + lofs[li] + pos] = (int)(p & 0x1FFFFu);
  }
}

// One wave per node: per relation gather xb[src] rows, mean in f32, write agg bf16.
// Scalarized segment bounds, 32-bit SGPR-base gather addressing, packed f32 add.
__global__ __launch_bounds__(256) void aggregate_kernel(
    const unsigned int* __restrict__ xb32, const int* __restrict__ ssrc,
    const int* __restrict__ offs, unsigned int* __restrict__ agg32,
    int rLo, int rHi, int slabBase) {
  int lane = threadIdx.x & 63;
  int n = blockIdx.x * 4 + (threadIdx.x >> 6);
  if (n >= N_NODES) return;
  for (int r = rLo; r < rHi; ++r) {
    int fl = r * N_NODES + n;
    int oidx = fl + (fl >> 10);   // bucket-strided offs index
    int start = __builtin_amdgcn_readfirstlane(offs[oidx]);
    int end = __builtin_amdgcn_readfirstlane(offs[oidx + 1]);
    int c = end - start;
    f32x2 acc = {0.f, 0.f};
    for (int e = start; e < end; e += 8) {
      int m = end - e;   // wave-uniform
      unsigned int v[8];
#pragma unroll
      for (int k = 0; k < 8; ++k) {
        int idx = ssrc[e + ((k < m) ? k : 0)];                 // uniform index
        v[k] = xb32[((unsigned)idx << 6) | (unsigned)lane];    // sgpr-base + voffset
      }
#pragma unroll
      for (int k = 0; k < 8; ++k) {
        unsigned int u = (k < m) ? v[k] : 0u;
        f32x2 d;
        d.x = __uint_as_float(u << 16);          // low bf16
        d.y = __uint_as_float(u & 0xffff0000u);  // high bf16
        acc += d;                                 // v_pk_add_f32
      }
    }
    float inv = __builtin_amdgcn_rcpf((float)(c > 0 ? c : 1));
    float lo = acc.x * inv, hi = acc.y * inv;
    unsigned int packed;
    asm("v_cvt_pk_bf16_f32 %0, %1, %2" : "=v"(packed) : "v"(lo), "v"(hi));
    agg32[((size_t)(r - slabBase) * N_NODES + n) * 64 + lane] = packed;
  }
}

// GEMM with LDS-staged B: the 32KB B-slab (shared by ALL waves) is staged into
// LDS once per block per slab and read via contiguous ds_read_b128 — this kills
// the 500 MB of per-wave hot-line Wt re-reads (3128 waves x 160 KB) that made the
// register-direct variant latency-bound at 5.8% MfmaUtil. A-fragments stay
// register-direct from global (each row read exactly once device-wide).
// No early return (barrier deadlock): invalid bands load row 0 and skip stores.
__global__ __launch_bounds__(256) void gemm_kernel(
    const unsigned short* __restrict__ xb, const unsigned short* __restrict__ Wt,
    const float* __restrict__ biasc, float* __restrict__ out,
    const unsigned short* __restrict__ agg, int slabBase, int bLo, int bHi, int accum) {
  __shared__ short8 Bs[2048];   // 32 KB: one B slab (4 ks x 8 ct x 64 lanes)
  int tid = threadIdx.x;
  int lane = tid & 63;
  int wv = __builtin_amdgcn_readfirstlane(tid >> 6);
  int bandRow = blockIdx.x * 128 + wv * 32;
  int valid = bandRow < N_NODES;           // wave-uniform (N_NODES % 32 == 0)
  int ldRow = valid ? bandRow : 0;
  int quad = lane >> 4;
  int lr = lane & 15;
  const short8* Bp = (const short8*)Wt;

  float bias8[8];
#pragma unroll
  for (int ct = 0; ct < 8; ++ct) bias8[ct] = biasc[ct * 16 + lr];

  f32x4 zero = {0.f, 0.f, 0.f, 0.f};
  f32x4 acc[2][8];
#pragma unroll
  for (int rt = 0; rt < 2; ++rt)
#pragma unroll
    for (int ct = 0; ct < 8; ++ct) acc[rt][ct] = zero;

  // stage first B slab
#pragma unroll
  for (int p = 0; p < 8; ++p) Bs[p * 256 + tid] = Bp[(size_t)bLo * 2048 + p * 256 + tid];
  __syncthreads();

  for (int bi = bLo; bi <= bHi; ++bi) {
    const unsigned short* as =
        (bi == 0) ? xb : agg + (size_t)(bi - 1 - slabBase) * N_NODES * DIM;
    const unsigned short* rowp = as + (size_t)(ldRow + lr) * DIM;
    short8 a0[4], a1[4];
#pragma unroll
    for (int ks = 0; ks < 4; ++ks) {
      int k0 = ks * 32 + quad * 8;
      a0[ks] = *(const short8*)(rowp + k0);
      a1[ks] = *(const short8*)(rowp + 16 * DIM + k0);
    }
#pragma unroll
    for (int ks = 0; ks < 4; ++ks) {
#pragma unroll
      for (int ct = 0; ct < 8; ++ct) {
        short8 bf = Bs[(ks * 8 + ct) * 64 + lane];
        acc[0][ct] = __builtin_amdgcn_mfma_f32_16x16x32_bf16(a0[ks], bf, acc[0][ct], 0, 0, 0);
        acc[1][ct] = __builtin_amdgcn_mfma_f32_16x16x32_bf16(a1[ks], bf, acc[1][ct], 0, 0, 0);
      }
    }
    if (bi < bHi) {
      __syncthreads();   // all waves done reading Bs
#pragma unroll
      for (int p = 0; p < 8; ++p)
        Bs[p * 256 + tid] = Bp[(size_t)(bi + 1) * 2048 + p * 256 + tid];
      __syncthreads();   // next slab visible
    }
  }

  if (valid) {
#pragma unroll
    for (int rt = 0; rt < 2; ++rt)
#pragma unroll
      for (int i = 0; i < 4; ++i) {
        int g = bandRow + rt * 16 + quad * 4 + i;
        if (accum == 0) {
#pragma unroll
          for (int ct = 0; ct < 8; ++ct)
            out[(size_t)g * DIM + ct * 16 + lr] = acc[rt][ct][i] + bias8[ct];
        } else {
#pragma unroll
          for (int ct = 0; ct < 8; ++ct)
            out[(size_t)g * DIM + ct * 16 + lr] += acc[rt][ct][i];
        }
      }
  }
}

extern "C" void kernel_launch(void* const* d_in, const int* in_sizes, int n_in,
                              void* d_out, int out_size, void* d_ws, size_t ws_size,
                              hipStream_t stream) {
  const float* x = (const float*)d_in[0];
  const int* src = (const int*)d_in[1];
  const int* dst = (const int*)d_in[2];
  const float* Wself = (const float*)d_in[3];
  const float* Wneigh = (const float*)d_in[4];
  const float* bv = (const float*)d_in[5];
  float* out = (float*)d_out;

  char* ws = (char*)d_ws;
  size_t off = 0;
  int* bcnt = (int*)(ws + off);        off += 2048;                                    // 391 cursors
  unsigned short* Wt = (unsigned short*)(ws + off);  off += 5 * DIM * DIM * 2;         // 160 KB
  float* biasc = (float*)(ws + off);   off += DIM * 4;
  int* offs = (int*)(ws + off);        off += ((size_t)NBK * (BSLOT + 1) * 4 + 15) & ~15;  // 1.6 MB
  unsigned short* xb = (unsigned short*)(ws + off);  off += (size_t)N_NODES * DIM * 2;  // 25.6 MB
  unsigned int* gpairs = (unsigned int*)(ws + off);  off += (size_t)NBK * CAP * 4;      // 12.8 MB
  int* ssrc = (int*)(ws + off);        off += (size_t)NBK * CAP * 4;                    // 12.8 MB
  unsigned short* agg = (unsigned short*)(ws + off);
  size_t slabBytes = (size_t)N_NODES * DIM * 2;                                         // 25.6 MB

  int sc = 0;
  while (sc < NREL && ws_size >= off + (size_t)(sc + 1) * slabBytes) sc++;
  if (sc < 1) sc = 1;

  hipMemsetAsync(bcnt, 0, 2048, stream);
  xb_kernel<<<(N_NODES * DIM / 4 + 255) / 256, 256, 0, stream>>>(x, xb);
  prep_kernel<<<(5 * DIM * DIM + 255) / 256, 256, 0, stream>>>(Wself, Wneigh, bv, Wt, biasc);
  bscatter_kernel<<<(TOT_E + CHUNK - 1) / CHUNK, 256, 0, stream>>>(src, dst, bcnt, gpairs);
  bfill_kernel<<<NBK, 256, 0, stream>>>(gpairs, bcnt, offs, ssrc);

  int gAgg = (N_NODES + 3) / 4;       // wave per node
  int gGemm = (N_NODES + 127) / 128;  // 782
  for (int r0 = 0; r0 < NREL; r0 += sc) {
    int cr = (NREL - r0 < sc) ? (NREL - r0) : sc;
    aggregate_kernel<<<gAgg, 256, 0, stream>>>((const unsigned int*)xb, ssrc, offs,
                                               (unsigned int*)agg, r0, r0 + cr, r0);
    int bLo = (r0 == 0) ? 0 : (1 + r0);
    gemm_kernel<<<gGemm, 256, 0, stream>>>(xb, Wt, biasc, out, agg, r0, bLo, r0 + cr,
                                           (r0 == 0) ? 0 : 1);
  }
}